// Round 10
// baseline (599.734 us; speedup 1.0000x reference)
//
#include <hip/hip_runtime.h>
#include <hip/hip_cooperative_groups.h>

namespace cg = cooperative_groups;

// RelationalKENN, R12 (resubmit; R9 bench was a broker timeout, no data).
// Single fused cooperative kernel (structural pivot).
//
// History: R5 bucket sort + LDS binning. R6-R8 block-private 8B-record slabs,
// zero global coordination: edge 102->56us. R9 occupancy 49->61%: edge FLAT
// (not occupancy-limited). R10 LDS-staged coalesced rec stores: WRITE 76->63MB,
// edge 57->48us, total 159.6. R11 nontemporal streams: NULL (FETCH/dur flat)
// -- L2-pollution theory dead. Edge pinned ~48us/~2TB/s across 7 shapes.
// Non-edge remainder ~115-125us is invisible (top-5 all edge) and constant
// across structural changes to bin/unary; bottom-up model says unary+bin+merge
// ~= 36us -> ~60-80us unexplained => suspect inter-kernel drain/launch overhead
// + recs/partials HBM round trips between kernels.
// R12: ONE cooperative kernel, 4 phases with __threadfence()+grid.sync()
// (device-scope fence emits L2 wb/inv on gfx950 -> cross-XCD safe). Removes
// 3 dispatch boundaries; recs/partials consumed L3-warm.
//
// Layout: d_out = [ up : n_nodes*16 fp32 | bp : n_edges*4 fp32 ]
// ws = [ recs | partials | u4 | cnts | offs ]

#define NRANGE 13
#define RBITS  13
#define RSIZE  8192            // nodes per range (1 << RBITS)
#define NSLICE 16
#define EPB    2048            // edges per chunk (1024 threads x 2)
#define FXP_SCALE 2048.0f      // 2^11; magnitudes <= 0.5 -> q <= 1024 (11b)
#define FXP_INV   (1.0f / 2048.0f)

// native clang vector for nontemporal store (HIP_vector_type is invalid there)
typedef float nf4 __attribute__((ext_vector_type(4)));

__device__ __forceinline__ void nt_store_f4(float4 v, float4* p) {
    nf4 t; t.x = v.x; t.y = v.y; t.z = v.z; t.w = v.w;
    __builtin_nontemporal_store(t, (nf4*)p);
}

__device__ __forceinline__ void sm2(float xi, float xj, float w,
                                    float& di, float& dj) {
    float na = -xi, b = xj;
    float m  = fmaxf(na, b);
    float e0 = __expf(na - m), e1 = __expf(b - m);
    float inv = w / (e0 + e1);
    di -= e0 * inv;
    dj += e1 * inv;
}

__device__ __forceinline__ void sm3(float xi, float xj, float xk, float w,
                                    float& di, float& dj, float& dk) {
    float na = -xi, b = xj, c = xk;
    float m  = fmaxf(fmaxf(na, b), c);
    float e0 = __expf(na - m), e1 = __expf(b - m), e2 = __expf(c - m);
    float inv = w / (e0 + e1 + e2);
    di -= e0 * inv;
    dj += e1 * inv;
    dk += e2 * inv;
}

// ---------- fast path: one cooperative kernel, 4 phases ----------

__global__ __launch_bounds__(1024, 8)     // 16 waves/block, 8 waves/EU -> 2 blk/CU
void fused_kernel(const float* __restrict__ x_in,
                  const float4* __restrict__ binary,
                  const int* __restrict__ idx1,
                  const int* __restrict__ idx2,
                  const float* __restrict__ uw,
                  const float* __restrict__ bw,
                  float* __restrict__ up,
                  float4* __restrict__ bp,
                  float4* __restrict__ u4,
                  unsigned long long* __restrict__ recs,     // [chunk][2][EPB]
                  unsigned* __restrict__ cnts,               // [chunk][2][NRANGE]
                  unsigned* __restrict__ offs,               // [chunk][2][NRANGE]
                  unsigned long long* __restrict__ partials, // [2*13*NSLICE][RSIZE]
                  int n_nodes, int n_edges, int nchunk) {
    __shared__ union SH {
        struct {
            unsigned cnt[2][NRANGE];
            unsigned off[2][NRANGE];
            unsigned long long stage[2][EPB];   // 32 KB
        } e;
        unsigned long long table[RSIZE];        // 64 KB
    } sh;

    cg::grid_group grid = cg::this_grid();
    const int tid     = threadIdx.x;
    const int nthread = gridDim.x * 1024;

    // ---- phase 1: unary enhance -> up, compact u4 ----
    for (int n = blockIdx.x * 1024 + tid; n < n_nodes; n += nthread) {
        const float4* xr = (const float4*)(x_in + (size_t)n * 16);
        float4 r0 = xr[0], r1 = xr[1], r2 = xr[2], r3 = xr[3];
        float x[16] = {r0.x, r0.y, r0.z, r0.w, r1.x, r1.y, r1.z, r1.w,
                       r2.x, r2.y, r2.z, r2.w, r3.x, r3.y, r3.z, r3.w};
        float d[16];
#pragma unroll
        for (int i = 0; i < 16; ++i) d[i] = 0.0f;
        sm2(x[0],  x[1],          uw[0], d[0],  d[1]);
        sm2(x[1],  x[2],          uw[1], d[1],  d[2]);
        sm3(x[2],  x[3],  x[4],   uw[2], d[2],  d[3],  d[4]);
        sm2(x[4],  x[5],          uw[3], d[4],  d[5]);
        sm3(x[6],  x[7],  x[8],   uw[4], d[6],  d[7],  d[8]);
        sm2(x[8],  x[9],          uw[5], d[8],  d[9]);
        sm3(x[10], x[11], x[12],  uw[6], d[10], d[11], d[12]);
        sm3(x[13], x[14], x[15],  uw[7], d[13], d[14], d[15]);
        float4* w_up = (float4*)(up + (size_t)n * 16);
        float4 v0 = make_float4(x[0]+d[0], x[1]+d[1], x[2]+d[2], x[3]+d[3]);
        w_up[0] = v0;
#pragma unroll
        for (int i = 1; i < 4; ++i)
            w_up[i] = make_float4(x[4*i]+d[4*i],     x[4*i+1]+d[4*i+1],
                                  x[4*i+2]+d[4*i+2], x[4*i+3]+d[4*i+3]);
        u4[n] = v0;
    }
    __threadfence();           // device-scope: L2 writeback for cross-XCD reads
    grid.sync();

    // ---- phase 2: edge compute + block-private bucket slabs ----
    {
        float w[4] = {bw[0], bw[1], bw[2], bw[3]};
        for (int chunk = blockIdx.x; chunk < nchunk; chunk += gridDim.x) {
            if (tid < 2 * NRANGE) ((unsigned*)sh.e.cnt)[tid] = 0;
            __syncthreads();

            int e[2]; bool valid[2];
            int i1[2], i2[2], r1[2], r2[2];
            unsigned rank1[2], rank2[2];
            unsigned long long q1[2], q2[2];
            float4 b4[2], a4[2], c4[2], dbv4[2];

#pragma unroll
            for (int k = 0; k < 2; ++k) {
                e[k] = chunk * EPB + k * 1024 + tid;
                valid[k] = e[k] < n_edges;
                int ec = valid[k] ? e[k] : 0;
                i1[k] = idx1[ec];
                i2[k] = idx2[ec];
            }
#pragma unroll
            for (int k = 0; k < 2; ++k) {        // 4 gathers + 2 streams in flight
                a4[k] = u4[i1[k]];
                c4[k] = u4[i2[k]];
                b4[k] = binary[valid[k] ? e[k] : 0];
            }
#pragma unroll
            for (int k = 0; k < 2; ++k) {
                float a[4]  = {a4[k].x, a4[k].y, a4[k].z, a4[k].w};
                float bb[4] = {b4[k].x, b4[k].y, b4[k].z, b4[k].w};
                float c[4]  = {c4[k].x, c4[k].y, c4[k].z, c4[k].w};
                unsigned p1[4], p2[4];
                float dbv[4];
#pragma unroll
                for (int i = 0; i < 4; ++i) {
                    // clause ([i, 32+i, 16+i], [-1,-1,+1]): sel = [-u1_i,-b_i,u2_i]
                    float na = -a[i], nb = -bb[i], cc = c[i];
                    float m  = fmaxf(fmaxf(na, nb), cc);
                    float e0 = __expf(na-m), e1 = __expf(nb-m), e2 = __expf(cc-m);
                    float inv = w[i] / (e0 + e1 + e2);
                    p1[i]  = __float2uint_rn(e0 * inv * FXP_SCALE);  // |du1|
                    p2[i]  = __float2uint_rn(e2 * inv * FXP_SCALE);  // du2
                    dbv[i] = bb[i] - e1 * inv;
                }
                q1[k] = (unsigned long long)(unsigned)(i1[k] & (RSIZE-1))
                      | ((unsigned long long)p1[0] << 13) | ((unsigned long long)p1[1] << 25)
                      | ((unsigned long long)p1[2] << 37) | ((unsigned long long)p1[3] << 49);
                q2[k] = (unsigned long long)(unsigned)(i2[k] & (RSIZE-1))
                      | ((unsigned long long)p2[0] << 13) | ((unsigned long long)p2[1] << 25)
                      | ((unsigned long long)p2[2] << 37) | ((unsigned long long)p2[3] << 49);
                dbv4[k] = make_float4(dbv[0], dbv[1], dbv[2], dbv[3]);
                r1[k] = i1[k] >> RBITS;
                r2[k] = i2[k] >> RBITS;
                if (valid[k]) {
                    rank1[k] = atomicAdd(&sh.e.cnt[0][r1[k]], 1u);   // LDS rank
                    rank2[k] = atomicAdd(&sh.e.cnt[1][r2[k]], 1u);
                }
            }
            __syncthreads();
            if (tid < 2) {                       // 13-entry exclusive scan/side
                unsigned acc = 0;
#pragma unroll
                for (int r = 0; r < NRANGE; ++r) {
                    sh.e.off[tid][r] = acc; acc += sh.e.cnt[tid][r];
                }
            }
            __syncthreads();
            if (tid < 2 * NRANGE) {              // publish counts + offsets
                cnts[(size_t)chunk * 2 * NRANGE + tid] = ((unsigned*)sh.e.cnt)[tid];
                offs[(size_t)chunk * 2 * NRANGE + tid] = ((unsigned*)sh.e.off)[tid];
            }
#pragma unroll
            for (int k = 0; k < 2; ++k) {        // rank-scatter into LDS stage
                if (!valid[k]) continue;
                sh.e.stage[0][sh.e.off[0][r1[k]] + rank1[k]] = q1[k];
                sh.e.stage[1][sh.e.off[1][r2[k]] + rank2[k]] = q2[k];
                nt_store_f4(dbv4[k], bp + e[k]);  // write-once output, bypass L2
            }
            __syncthreads();
            // stream slab out coalesced (plain stores: keep L2/L3-warm for bin)
            ulonglong2* dst = (ulonglong2*)(recs + (size_t)chunk * 2 * EPB);
            const ulonglong2* s0 = (const ulonglong2*)sh.e.stage[0];
            const ulonglong2* s1 = (const ulonglong2*)sh.e.stage[1];
            dst[tid]        = s0[tid];
            dst[1024 + tid] = s1[tid];
        }
    }
    __threadfence();
    grid.sync();

    // ---- phase 3: bin records into per-(side,range,slice) LDS tables ----
    for (int b = blockIdx.x; b < 2 * NRANGE * NSLICE; b += gridDim.x) {
        unsigned s    = (unsigned)b % NSLICE;
        unsigned rr   = ((unsigned)b / NSLICE) % NRANGE;
        unsigned side = (unsigned)b / (NSLICE * NRANGE);

        for (int i = tid; i < RSIZE; i += 1024) sh.table[i] = 0ull;
        __syncthreads();

        unsigned bpg = ((unsigned)nchunk + NSLICE - 1) / NSLICE;
        unsigned b0 = s * bpg;
        unsigned b1 = b0 + bpg;
        if (b1 > (unsigned)nchunk) b1 = (unsigned)nchunk;

        unsigned wid  = (unsigned)tid >> 6;      // 16 waves, independent segs
        unsigned lane = (unsigned)tid & 63;
        unsigned eb = b0 + wid;
        unsigned c_cur = 0, o_cur = 0;
        if (eb < b1) {
            unsigned base = (eb * 2u + side) * NRANGE + rr;
            c_cur = cnts[base];
            o_cur = offs[base];
        }
        while (eb < b1) {
            unsigned eb_n = eb + 16;             // prefetch next descriptor
            unsigned c_n = 0, o_n = 0;
            if (eb_n < b1) {
                unsigned base_n = (eb_n * 2u + side) * NRANGE + rr;
                c_n = cnts[base_n];
                o_n = offs[base_n];
            }
            const unsigned long long* seg =
                recs + ((size_t)eb * 2 + side) * EPB + o_cur;
            unsigned i = lane;
            for (; i + 64 < c_cur; i += 128) {   // 2 loads in flight
                unsigned long long ra = seg[i];
                unsigned long long rb = seg[i + 64];
                unsigned long long va =  ((ra >> 13) & 0xFFFull)
                                      | (((ra >> 25) & 0xFFFull) << 16)
                                      | (((ra >> 37) & 0xFFFull) << 32)
                                      | (((ra >> 49) & 0xFFFull) << 48);
                unsigned long long vb =  ((rb >> 13) & 0xFFFull)
                                      | (((rb >> 25) & 0xFFFull) << 16)
                                      | (((rb >> 37) & 0xFFFull) << 32)
                                      | (((rb >> 49) & 0xFFFull) << 48);
                atomicAdd(&sh.table[(unsigned)ra & (RSIZE - 1)], va);
                atomicAdd(&sh.table[(unsigned)rb & (RSIZE - 1)], vb);
            }
            if (i < c_cur) {
                unsigned long long ra = seg[i];
                unsigned long long va =  ((ra >> 13) & 0xFFFull)
                                      | (((ra >> 25) & 0xFFFull) << 16)
                                      | (((ra >> 37) & 0xFFFull) << 32)
                                      | (((ra >> 49) & 0xFFFull) << 48);
                atomicAdd(&sh.table[(unsigned)ra & (RSIZE - 1)], va);
            }
            eb = eb_n;
            c_cur = c_n;
            o_cur = o_n;
        }
        __syncthreads();

        unsigned long long* dst = partials + (size_t)b * RSIZE;
        for (int i2 = tid; i2 < RSIZE; i2 += 1024) dst[i2] = sh.table[i2];
        __syncthreads();                         // table reuse guard
    }
    __threadfence();
    grid.sync();

    // ---- phase 4: merge partials into up ----
    for (int n = blockIdx.x * 1024 + tid; n < n_nodes; n += nthread) {
        unsigned rr = (unsigned)n >> RBITS;
        unsigned i  = (unsigned)n & (RSIZE - 1);
        const unsigned long long* pn =
            partials + ((size_t)(0 * NRANGE + rr) * NSLICE) * RSIZE + i;
        const unsigned long long* pp =
            partials + ((size_t)(1 * NRANGE + rr) * NSLICE) * RSIZE + i;
        unsigned long long qn = 0, qp = 0;
#pragma unroll
        for (int sl = 0; sl < NSLICE; ++sl) {
            qn += pn[(size_t)sl * RSIZE];
            qp += pp[(size_t)sl * RSIZE];
        }
        float4* dst = (float4*)(up + (size_t)n * 16);
        float4 cur = dst[0];
        float d0 = ((float)(unsigned)( qp        & 0xFFFF) -
                    (float)(unsigned)( qn        & 0xFFFF)) * FXP_INV;
        float d1 = ((float)(unsigned)((qp >> 16) & 0xFFFF) -
                    (float)(unsigned)((qn >> 16) & 0xFFFF)) * FXP_INV;
        float d2 = ((float)(unsigned)((qp >> 32) & 0xFFFF) -
                    (float)(unsigned)((qn >> 32) & 0xFFFF)) * FXP_INV;
        float d3 = ((float)(unsigned)((qp >> 48) & 0xFFFF) -
                    (float)(unsigned)((qn >> 48) & 0xFFFF)) * FXP_INV;
        dst[0] = make_float4(cur.x + d0, cur.y + d1, cur.z + d2, cur.w + d3);
    }
}

// ---------- fallback path (R4, proven): packed u64 global atomics ----------

__global__ void unary_kernel(const float* __restrict__ x_in,
                             const float* __restrict__ uw,
                             float* __restrict__ up,
                             float4* __restrict__ u4,
                             int n_nodes) {
    int n = blockIdx.x * blockDim.x + threadIdx.x;
    if (n >= n_nodes) return;
    const float4* xr = (const float4*)(x_in + (size_t)n * 16);
    float4 r0 = xr[0], r1 = xr[1], r2 = xr[2], r3 = xr[3];
    float x[16] = {r0.x, r0.y, r0.z, r0.w, r1.x, r1.y, r1.z, r1.w,
                   r2.x, r2.y, r2.z, r2.w, r3.x, r3.y, r3.z, r3.w};
    float d[16];
#pragma unroll
    for (int i = 0; i < 16; ++i) d[i] = 0.0f;
    sm2(x[0],  x[1],          uw[0], d[0],  d[1]);
    sm2(x[1],  x[2],          uw[1], d[1],  d[2]);
    sm3(x[2],  x[3],  x[4],   uw[2], d[2],  d[3],  d[4]);
    sm2(x[4],  x[5],          uw[3], d[4],  d[5]);
    sm3(x[6],  x[7],  x[8],   uw[4], d[6],  d[7],  d[8]);
    sm2(x[8],  x[9],          uw[5], d[8],  d[9]);
    sm3(x[10], x[11], x[12],  uw[6], d[10], d[11], d[12]);
    sm3(x[13], x[14], x[15],  uw[7], d[13], d[14], d[15]);
    float4* w_up = (float4*)(up + (size_t)n * 16);
    float4 v0 = make_float4(x[0]+d[0], x[1]+d[1], x[2]+d[2], x[3]+d[3]);
    w_up[0] = v0;
#pragma unroll
    for (int i = 1; i < 4; ++i)
        w_up[i] = make_float4(x[4*i]+d[4*i],     x[4*i+1]+d[4*i+1],
                              x[4*i+2]+d[4*i+2], x[4*i+3]+d[4*i+3]);
    u4[n] = v0;
}

__global__ void edge_atomic_kernel(const float* __restrict__ u,
                                   const float4* __restrict__ binary,
                                   const int* __restrict__ idx1,
                                   const int* __restrict__ idx2,
                                   const float* __restrict__ bw,
                                   unsigned long long* __restrict__ neg,
                                   unsigned long long* __restrict__ pos,
                                   float4* __restrict__ bp,
                                   int n_edges) {
    int e = blockIdx.x * blockDim.x + threadIdx.x;
    if (e >= n_edges) return;
    int n1 = idx1[e], n2 = idx2[e];
    float4 b4 = binary[e];
    float4 a4 = *(const float4*)(u + (size_t)n1 * 16);
    float4 c4 = *(const float4*)(u + (size_t)n2 * 16);
    float a[4]  = {a4.x, a4.y, a4.z, a4.w};
    float bb[4] = {b4.x, b4.y, b4.z, b4.w};
    float c[4]  = {c4.x, c4.y, c4.z, c4.w};
    unsigned long long q1 = 0, q2 = 0;
    float dbv[4];
#pragma unroll
    for (int i = 0; i < 4; ++i) {
        float na = -a[i], nb = -bb[i], cc = c[i];
        float m  = fmaxf(fmaxf(na, nb), cc);
        float e0 = __expf(na-m), e1 = __expf(nb-m), e2 = __expf(cc-m);
        float inv = bw[i] / (e0 + e1 + e2);
        q1 |= (unsigned long long)__float2uint_rn(e0 * inv * FXP_SCALE) << (16 * i);
        q2 |= (unsigned long long)__float2uint_rn(e2 * inv * FXP_SCALE) << (16 * i);
        dbv[i] = bb[i] - e1 * inv;
    }
    atomicAdd(&neg[n1], q1);
    atomicAdd(&pos[n2], q2);
    bp[e] = make_float4(dbv[0], dbv[1], dbv[2], dbv[3]);
}

__global__ void merge_atomic_kernel(const unsigned long long* __restrict__ neg,
                                    const unsigned long long* __restrict__ pos,
                                    float* __restrict__ up, int n_nodes) {
    int n = blockIdx.x * blockDim.x + threadIdx.x;
    if (n >= n_nodes) return;
    unsigned long long qn = neg[n], qp = pos[n];
    float4* dst = (float4*)(up + (size_t)n * 16);
    float4 cur = dst[0];
    float d0 = ((float)(unsigned)( qp        & 0xFFFF) -
                (float)(unsigned)( qn        & 0xFFFF)) * FXP_INV;
    float d1 = ((float)(unsigned)((qp >> 16) & 0xFFFF) -
                (float)(unsigned)((qn >> 16) & 0xFFFF)) * FXP_INV;
    float d2 = ((float)(unsigned)((qp >> 32) & 0xFFFF) -
                (float)(unsigned)((qn >> 32) & 0xFFFF)) * FXP_INV;
    float d3 = ((float)(unsigned)((qp >> 48) & 0xFFFF) -
                (float)(unsigned)((qn >> 48) & 0xFFFF)) * FXP_INV;
    dst[0] = make_float4(cur.x + d0, cur.y + d1, cur.z + d2, cur.w + d3);
}

extern "C" void kernel_launch(void* const* d_in, const int* in_sizes, int n_in,
                              void* d_out, int out_size, void* d_ws, size_t ws_size,
                              hipStream_t stream) {
    const float* unary   = (const float*)d_in[0];
    const float* binary  = (const float*)d_in[1];
    const int*   index1  = (const int*)d_in[2];
    const int*   index2  = (const int*)d_in[3];
    const float* uw      = (const float*)d_in[4];
    const float* bw      = (const float*)d_in[5];

    int n_nodes = in_sizes[0] / 16;
    int n_edges = in_sizes[2];

    float* out = (float*)d_out;
    float* up  = out;                                // n_nodes*16
    float* bp  = out + (size_t)n_nodes * 16;         // n_edges*4

    int nchunk = (n_edges + EPB - 1) / EPB;

    // ws layout (fast path): recs | partials | u4 | cnts | offs
    size_t rec_bytes  = (size_t)nchunk * 2 * EPB * 8;                    // 32.0 MB
    size_t part_bytes = (size_t)2 * NRANGE * NSLICE * RSIZE * 8;         // 27.26 MB
    size_t u4_bytes   = (size_t)n_nodes * 16;                            // 1.6 MB
    size_t cnt_bytes  = (size_t)nchunk * 2 * NRANGE * 4;                 // ~102 KB
    size_t need = rec_bytes + part_bytes + u4_bytes + 2 * cnt_bytes + 256;

    if (ws_size >= need) {
        char* w = (char*)d_ws;
        unsigned long long* recs     = (unsigned long long*)w;
        unsigned long long* partials = (unsigned long long*)(w + rec_bytes);
        float4*   u4   = (float4*)(w + rec_bytes + part_bytes);
        unsigned* cnts = (unsigned*)(w + rec_bytes + part_bytes + u4_bytes);
        unsigned* offs = cnts + (size_t)nchunk * 2 * NRANGE;

        const float4* binary4 = (const float4*)binary;
        float4* bp4 = (float4*)bp;

        int num_cu = 256;
        (void)hipDeviceGetAttribute(&num_cu, hipDeviceAttributeMultiprocessorCount, 0);
        int maxblk = 2;
        (void)hipOccupancyMaxActiveBlocksPerMultiprocessor(&maxblk, fused_kernel,
                                                           1024, 0);
        if (maxblk < 1) maxblk = 1;
        if (maxblk > 2) maxblk = 2;
        int grid = num_cu * maxblk;                   // expect 512 on MI355X

        void* args[] = {
            (void*)&unary, (void*)&binary4, (void*)&index1, (void*)&index2,
            (void*)&uw, (void*)&bw, (void*)&up, (void*)&bp4, (void*)&u4,
            (void*)&recs, (void*)&cnts, (void*)&offs, (void*)&partials,
            (void*)&n_nodes, (void*)&n_edges, (void*)&nchunk
        };
        (void)hipLaunchCooperativeKernel((const void*)fused_kernel,
                                         dim3(grid), dim3(1024),
                                         args, 0, stream);
    } else {
        // R4 fallback: packed u64 atomics (proven)
        unsigned long long* neg = (unsigned long long*)d_ws;
        unsigned long long* pos = neg + n_nodes;
        float4* u4 = (float4*)(pos + n_nodes);
        (void)hipMemsetAsync(neg, 0, (size_t)2 * n_nodes * 8, stream);
        unary_kernel<<<(n_nodes + 255) / 256, 256, 0, stream>>>(
            unary, uw, up, u4, n_nodes);
        edge_atomic_kernel<<<(n_edges + 255) / 256, 256, 0, stream>>>(
            up, (const float4*)binary, index1, index2, bw,
            neg, pos, (float4*)bp, n_edges);
        merge_atomic_kernel<<<(n_nodes + 255) / 256, 256, 0, stream>>>(
            neg, pos, up, n_nodes);
    }
}

// Round 12
// 163.990 us; speedup vs baseline: 3.6571x; 3.6571x over previous
//
#include <hip/hip_runtime.h>
#include <hip/hip_bf16.h>

// RelationalKENN, R13 (resubmit; R11-round bench was a broker timeout).
// Revert to R10 (proven 159.6us) + NSLICE 16->8.
//
// History: R5 bucket sort + LDS binning. R6-R8 block-private 8B-record
// slabs, zero global coordination: edge 102->56us. R9 occupancy 49->61%:
// edge FLAT (not occupancy-limited). R10 LDS-staged coalesced rec stores:
// WRITE 76->63MB, edge 57->48us, total 159.6 (best). R11 nontemporal: NULL
// (L2-pollution theory dead). R12 fused cooperative kernel: CATASTROPHIC
// (905us dispatch, VALU 1.5%, 0.2TB/s @ 97% occupancy) -- grid.sync spin
// across 8 non-coherent XCD L2s + per-wave device-fence L2 writebacks.
// Cooperative grid fusion is NOT viable on gfx950 at this scale.
// R13: single variable vs R10 -- NSLICE 16->8. Partials 27.3->13.6MB:
// bin writes half, merge reads half, bin zeroing halves. Probes whether
// bin+merge are the hidden bulk of the ~110us non-edge time.
// Predict: total -> ~148-153 (modeled); <140 => bin/merge heavy, push on;
// flat => launch/harness overhead dominates, near structural ceiling.
//
// Layout: d_out = [ up : n_nodes*16 fp32 | bp : n_edges*4 fp32 ]
// ws = [ recs | partials | u4 | cnts | offs ]

#define NRANGE 13
#define RBITS  13
#define RSIZE  8192            // nodes per range (1 << RBITS)
#define NSLICE 8
#define EPB    1024            // edges per block (512 threads x 2)
#define SEGCAP 1024            // records per side per block slab
#define FXP_SCALE 2048.0f      // 2^11; magnitudes <= 0.5 -> q <= 1024 (11b)
#define FXP_INV   (1.0f / 2048.0f)

__device__ __forceinline__ void sm2(float xi, float xj, float w,
                                    float& di, float& dj) {
    float na = -xi, b = xj;
    float m  = fmaxf(na, b);
    float e0 = __expf(na - m), e1 = __expf(b - m);
    float inv = w / (e0 + e1);
    di -= e0 * inv;
    dj += e1 * inv;
}

__device__ __forceinline__ void sm3(float xi, float xj, float xk, float w,
                                    float& di, float& dj, float& dk) {
    float na = -xi, b = xj, c = xk;
    float m  = fmaxf(fmaxf(na, b), c);
    float e0 = __expf(na - m), e1 = __expf(b - m), e2 = __expf(c - m);
    float inv = w / (e0 + e1 + e2);
    di -= e0 * inv;
    dj += e1 * inv;
    dk += e2 * inv;
}

__global__ void unary_kernel(const float* __restrict__ x_in,
                             const float* __restrict__ uw,
                             float* __restrict__ up,
                             float4* __restrict__ u4,      // compact cols 0..3
                             int n_nodes) {
    int n = blockIdx.x * blockDim.x + threadIdx.x;
    if (n >= n_nodes) return;

    const float4* xr = (const float4*)(x_in + (size_t)n * 16);
    float4 r0 = xr[0], r1 = xr[1], r2 = xr[2], r3 = xr[3];
    float x[16] = {r0.x, r0.y, r0.z, r0.w,
                   r1.x, r1.y, r1.z, r1.w,
                   r2.x, r2.y, r2.z, r2.w,
                   r3.x, r3.y, r3.z, r3.w};
    float d[16];
#pragma unroll
    for (int i = 0; i < 16; ++i) d[i] = 0.0f;

    sm2(x[0],  x[1],          uw[0], d[0],  d[1]);
    sm2(x[1],  x[2],          uw[1], d[1],  d[2]);
    sm3(x[2],  x[3],  x[4],   uw[2], d[2],  d[3],  d[4]);
    sm2(x[4],  x[5],          uw[3], d[4],  d[5]);
    sm3(x[6],  x[7],  x[8],   uw[4], d[6],  d[7],  d[8]);
    sm2(x[8],  x[9],          uw[5], d[8],  d[9]);
    sm3(x[10], x[11], x[12],  uw[6], d[10], d[11], d[12]);
    sm3(x[13], x[14], x[15],  uw[7], d[13], d[14], d[15]);

    float4* w_up = (float4*)(up + (size_t)n * 16);
    float4 v0 = make_float4(x[0] + d[0], x[1] + d[1], x[2] + d[2], x[3] + d[3]);
    w_up[0] = v0;
#pragma unroll
    for (int i = 1; i < 4; ++i)
        w_up[i] = make_float4(x[4*i]   + d[4*i],   x[4*i+1] + d[4*i+1],
                              x[4*i+2] + d[4*i+2], x[4*i+3] + d[4*i+3]);
    u4[n] = v0;
}

// ---------- fast path ----------

__global__ __launch_bounds__(512)
void edge_compute_kernel(const float4* __restrict__ u4,
                         const float4* __restrict__ binary,
                         const int* __restrict__ idx1,
                         const int* __restrict__ idx2,
                         const float* __restrict__ bw,
                         unsigned long long* __restrict__ recs, // [blk][2][SEGCAP]
                         unsigned* __restrict__ cnts,           // [blk][2][NRANGE]
                         unsigned* __restrict__ offs,           // [blk][2][NRANGE]
                         float4* __restrict__ bp,
                         int n_edges) {
    __shared__ unsigned cnt[2][NRANGE];
    __shared__ unsigned off[2][NRANGE];
    __shared__ __align__(16) unsigned long long stage[2][SEGCAP];  // 16 KB
    int tid = threadIdx.x;
    if (tid < 2 * NRANGE) ((unsigned*)cnt)[tid] = 0;
    __syncthreads();

    float w[4] = {bw[0], bw[1], bw[2], bw[3]};

    int e[2]; bool valid[2];
    int i1[2], i2[2], r1[2], r2[2];
    unsigned rank1[2], rank2[2];
    unsigned long long q1[2], q2[2];
    float4 b4[2], a4[2], c4[2], dbv4[2];

#pragma unroll
    for (int k = 0; k < 2; ++k) {
        e[k] = blockIdx.x * EPB + k * 512 + tid;
        valid[k] = e[k] < n_edges;
        int ec = valid[k] ? e[k] : 0;
        i1[k] = idx1[ec];
        i2[k] = idx2[ec];
    }
#pragma unroll
    for (int k = 0; k < 2; ++k) {          // 4 gathers + 2 streams in flight
        a4[k] = u4[i1[k]];
        c4[k] = u4[i2[k]];
        b4[k] = binary[valid[k] ? e[k] : 0];
    }

#pragma unroll
    for (int k = 0; k < 2; ++k) {
        float a[4]  = {a4[k].x, a4[k].y, a4[k].z, a4[k].w};
        float bb[4] = {b4[k].x, b4[k].y, b4[k].z, b4[k].w};
        float c[4]  = {c4[k].x, c4[k].y, c4[k].z, c4[k].w};
        unsigned p1[4], p2[4];
        float dbv[4];
#pragma unroll
        for (int i = 0; i < 4; ++i) {
            // clause ([i, 32+i, 16+i], [-1,-1,+1]): sel = [-u1_i, -b_i, u2_i]
            float na = -a[i], nb = -bb[i], cc = c[i];
            float m  = fmaxf(fmaxf(na, nb), cc);
            float e0 = __expf(na - m), e1 = __expf(nb - m), e2 = __expf(cc - m);
            float inv = w[i] / (e0 + e1 + e2);
            p1[i]  = __float2uint_rn(e0 * inv * FXP_SCALE);  // |du1|
            p2[i]  = __float2uint_rn(e2 * inv * FXP_SCALE);  // du2
            dbv[i] = bb[i] - e1 * inv;
        }
        q1[k] = (unsigned long long)(unsigned)(i1[k] & (RSIZE - 1))
              | ((unsigned long long)p1[0] << 13) | ((unsigned long long)p1[1] << 25)
              | ((unsigned long long)p1[2] << 37) | ((unsigned long long)p1[3] << 49);
        q2[k] = (unsigned long long)(unsigned)(i2[k] & (RSIZE - 1))
              | ((unsigned long long)p2[0] << 13) | ((unsigned long long)p2[1] << 25)
              | ((unsigned long long)p2[2] << 37) | ((unsigned long long)p2[3] << 49);
        dbv4[k] = make_float4(dbv[0], dbv[1], dbv[2], dbv[3]);
        r1[k] = i1[k] >> RBITS;
        r2[k] = i2[k] >> RBITS;
        if (valid[k]) {
            rank1[k] = atomicAdd(&cnt[0][r1[k]], 1u);   // LDS atomic rank
            rank2[k] = atomicAdd(&cnt[1][r2[k]], 1u);
        }
    }
    __syncthreads();
    if (tid < 2) {                          // 13-entry exclusive scan per side
        unsigned acc = 0;
#pragma unroll
        for (int r = 0; r < NRANGE; ++r) { off[tid][r] = acc; acc += cnt[tid][r]; }
    }
    __syncthreads();
    if (tid < 2 * NRANGE) {                 // publish counts + offsets
        cnts[(size_t)blockIdx.x * 2 * NRANGE + tid] = ((unsigned*)cnt)[tid];
        offs[(size_t)blockIdx.x * 2 * NRANGE + tid] = ((unsigned*)off)[tid];
    }
#pragma unroll
    for (int k = 0; k < 2; ++k) {           // rank-scatter into LDS stage
        if (!valid[k]) continue;
        stage[0][off[0][r1[k]] + rank1[k]] = q1[k];
        stage[1][off[1][r2[k]] + rank2[k]] = q2[k];
        bp[e[k]] = dbv4[k];
    }
    __syncthreads();
    // stream slab out fully coalesced: 512 thr x 16B per side
    ulonglong2* dst = (ulonglong2*)(recs + (size_t)blockIdx.x * 2 * SEGCAP);
    dst[tid]       = ((const ulonglong2*)stage[0])[tid];
    dst[512 + tid] = ((const ulonglong2*)stage[1])[tid];
}

__global__ __launch_bounds__(1024)
void bin_kernel(const unsigned long long* __restrict__ recs,
                const unsigned* __restrict__ cnts,
                const unsigned* __restrict__ offs,
                unsigned long long* __restrict__ partials,
                int nblk) {
    __shared__ unsigned long long table[RSIZE];   // 64 KB static
    unsigned b    = blockIdx.x;                   // (side*NRANGE + r)*NSLICE + s
    unsigned s    = b % NSLICE;
    unsigned rr   = (b / NSLICE) % NRANGE;
    unsigned side = b / (NSLICE * NRANGE);

    for (int i = threadIdx.x; i < RSIZE; i += 1024) table[i] = 0ull;
    __syncthreads();

    unsigned bpg = ((unsigned)nblk + NSLICE - 1) / NSLICE;
    unsigned b0 = s * bpg;
    unsigned b1 = b0 + bpg;
    if (b1 > (unsigned)nblk) b1 = (unsigned)nblk;

    unsigned wid  = threadIdx.x >> 6;             // 16 waves walk independent
    unsigned lane = threadIdx.x & 63;             // sub-segments, stride 16
    unsigned eb = b0 + wid;
    unsigned c_cur = 0, o_cur = 0;
    if (eb < b1) {
        unsigned base = (eb * 2u + side) * NRANGE + rr;
        c_cur = cnts[base];
        o_cur = offs[base];
    }
    while (eb < b1) {
        unsigned eb_n = eb + 16;                  // prefetch next descriptor
        unsigned c_n = 0, o_n = 0;
        if (eb_n < b1) {
            unsigned base_n = (eb_n * 2u + side) * NRANGE + rr;
            c_n = cnts[base_n];
            o_n = offs[base_n];
        }
        const unsigned long long* seg =
            recs + ((size_t)eb * 2 + side) * SEGCAP + o_cur;
        unsigned i = lane;
        for (; i + 64 < c_cur; i += 128) {        // 2 loads in flight
            unsigned long long ra = seg[i];
            unsigned long long rb = seg[i + 64];
            unsigned long long va =  ((ra >> 13) & 0xFFFull)
                                  | (((ra >> 25) & 0xFFFull) << 16)
                                  | (((ra >> 37) & 0xFFFull) << 32)
                                  | (((ra >> 49) & 0xFFFull) << 48);
            unsigned long long vb =  ((rb >> 13) & 0xFFFull)
                                  | (((rb >> 25) & 0xFFFull) << 16)
                                  | (((rb >> 37) & 0xFFFull) << 32)
                                  | (((rb >> 49) & 0xFFFull) << 48);
            atomicAdd(&table[(unsigned)ra & (RSIZE - 1)], va);
            atomicAdd(&table[(unsigned)rb & (RSIZE - 1)], vb);
        }
        if (i < c_cur) {
            unsigned long long ra = seg[i];
            unsigned long long va =  ((ra >> 13) & 0xFFFull)
                                  | (((ra >> 25) & 0xFFFull) << 16)
                                  | (((ra >> 37) & 0xFFFull) << 32)
                                  | (((ra >> 49) & 0xFFFull) << 48);
            atomicAdd(&table[(unsigned)ra & (RSIZE - 1)], va);
        }
        eb = eb_n;
        c_cur = c_n;
        o_cur = o_n;
    }
    __syncthreads();

    unsigned long long* dst = partials + (size_t)b * RSIZE;
    for (int i2 = threadIdx.x; i2 < RSIZE; i2 += 1024) dst[i2] = table[i2];
}

__global__ void merge_bin_kernel(const unsigned long long* __restrict__ partials,
                                 float* __restrict__ up, int n_nodes) {
    int n = blockIdx.x * blockDim.x + threadIdx.x;
    if (n >= n_nodes) return;
    unsigned rr = (unsigned)n >> RBITS;
    unsigned i  = (unsigned)n & (RSIZE - 1);

    const unsigned long long* pn =
        partials + ((size_t)(0 * NRANGE + rr) * NSLICE) * RSIZE + i;
    const unsigned long long* pp =
        partials + ((size_t)(1 * NRANGE + rr) * NSLICE) * RSIZE + i;
    unsigned long long qn = 0, qp = 0;
#pragma unroll
    for (int sl = 0; sl < NSLICE; ++sl) {
        qn += pn[(size_t)sl * RSIZE];
        qp += pp[(size_t)sl * RSIZE];
    }

    float4* dst = (float4*)(up + (size_t)n * 16);
    float4 cur = dst[0];
    float d0 = ((float)(unsigned)( qp        & 0xFFFF) -
                (float)(unsigned)( qn        & 0xFFFF)) * FXP_INV;
    float d1 = ((float)(unsigned)((qp >> 16) & 0xFFFF) -
                (float)(unsigned)((qn >> 16) & 0xFFFF)) * FXP_INV;
    float d2 = ((float)(unsigned)((qp >> 32) & 0xFFFF) -
                (float)(unsigned)((qn >> 32) & 0xFFFF)) * FXP_INV;
    float d3 = ((float)(unsigned)((qp >> 48) & 0xFFFF) -
                (float)(unsigned)((qn >> 48) & 0xFFFF)) * FXP_INV;
    dst[0] = make_float4(cur.x + d0, cur.y + d1, cur.z + d2, cur.w + d3);
}

// ---------- fallback path (R4, proven): packed u64 global atomics ----------

__global__ void edge_atomic_kernel(const float* __restrict__ u,
                                   const float4* __restrict__ binary,
                                   const int* __restrict__ idx1,
                                   const int* __restrict__ idx2,
                                   const float* __restrict__ bw,
                                   unsigned long long* __restrict__ neg,
                                   unsigned long long* __restrict__ pos,
                                   float4* __restrict__ bp,
                                   int n_edges) {
    int e = blockIdx.x * blockDim.x + threadIdx.x;
    if (e >= n_edges) return;
    int n1 = idx1[e], n2 = idx2[e];
    float4 b4 = binary[e];
    float4 a4 = *(const float4*)(u + (size_t)n1 * 16);
    float4 c4 = *(const float4*)(u + (size_t)n2 * 16);
    float a[4]  = {a4.x, a4.y, a4.z, a4.w};
    float bb[4] = {b4.x, b4.y, b4.z, b4.w};
    float c[4]  = {c4.x, c4.y, c4.z, c4.w};
    unsigned long long q1 = 0, q2 = 0;
    float dbv[4];
#pragma unroll
    for (int i = 0; i < 4; ++i) {
        float na = -a[i], nb = -bb[i], cc = c[i];
        float m  = fmaxf(fmaxf(na, nb), cc);
        float e0 = __expf(na - m), e1 = __expf(nb - m), e2 = __expf(cc - m);
        float inv = bw[i] / (e0 + e1 + e2);
        q1 |= (unsigned long long)__float2uint_rn(e0 * inv * FXP_SCALE) << (16 * i);
        q2 |= (unsigned long long)__float2uint_rn(e2 * inv * FXP_SCALE) << (16 * i);
        dbv[i] = bb[i] - e1 * inv;
    }
    atomicAdd(&neg[n1], q1);
    atomicAdd(&pos[n2], q2);
    bp[e] = make_float4(dbv[0], dbv[1], dbv[2], dbv[3]);
}

__global__ void merge_atomic_kernel(const unsigned long long* __restrict__ neg,
                                    const unsigned long long* __restrict__ pos,
                                    float* __restrict__ up, int n_nodes) {
    int n = blockIdx.x * blockDim.x + threadIdx.x;
    if (n >= n_nodes) return;
    unsigned long long qn = neg[n], qp = pos[n];
    float4* dst = (float4*)(up + (size_t)n * 16);
    float4 cur = dst[0];
    float d0 = ((float)(unsigned)( qp        & 0xFFFF) -
                (float)(unsigned)( qn        & 0xFFFF)) * FXP_INV;
    float d1 = ((float)(unsigned)((qp >> 16) & 0xFFFF) -
                (float)(unsigned)((qn >> 16) & 0xFFFF)) * FXP_INV;
    float d2 = ((float)(unsigned)((qp >> 32) & 0xFFFF) -
                (float)(unsigned)((qn >> 32) & 0xFFFF)) * FXP_INV;
    float d3 = ((float)(unsigned)((qp >> 48) & 0xFFFF) -
                (float)(unsigned)((qn >> 48) & 0xFFFF)) * FXP_INV;
    dst[0] = make_float4(cur.x + d0, cur.y + d1, cur.z + d2, cur.w + d3);
}

extern "C" void kernel_launch(void* const* d_in, const int* in_sizes, int n_in,
                              void* d_out, int out_size, void* d_ws, size_t ws_size,
                              hipStream_t stream) {
    const float* unary   = (const float*)d_in[0];
    const float* binary  = (const float*)d_in[1];
    const int*   index1  = (const int*)d_in[2];
    const int*   index2  = (const int*)d_in[3];
    const float* uw      = (const float*)d_in[4];
    const float* bw      = (const float*)d_in[5];

    int n_nodes = in_sizes[0] / 16;
    int n_edges = in_sizes[2];

    float* out = (float*)d_out;
    float* up  = out;                                // n_nodes*16
    float* bp  = out + (size_t)n_nodes * 16;         // n_edges*4

    int nblk = (n_edges + EPB - 1) / EPB;

    // ws layout (fast path): recs | partials | u4 | cnts | offs
    size_t rec_bytes  = (size_t)nblk * 2 * SEGCAP * 8;                   // 32.0 MB
    size_t part_bytes = (size_t)2 * NRANGE * NSLICE * RSIZE * 8;         // 13.6 MB
    size_t u4_bytes   = (size_t)n_nodes * 16;                            // 1.6 MB
    size_t cnt_bytes  = (size_t)nblk * 2 * NRANGE * 4;                   // ~203 KB
    size_t need = rec_bytes + part_bytes + u4_bytes + 2 * cnt_bytes + 256;

    if (ws_size >= need) {
        char* w = (char*)d_ws;
        unsigned long long* recs     = (unsigned long long*)w;
        unsigned long long* partials = (unsigned long long*)(w + rec_bytes);
        float4*   u4   = (float4*)(w + rec_bytes + part_bytes);
        unsigned* cnts = (unsigned*)(w + rec_bytes + part_bytes + u4_bytes);
        unsigned* offs = cnts + (size_t)nblk * 2 * NRANGE;

        unary_kernel<<<(n_nodes + 255) / 256, 256, 0, stream>>>(
            unary, uw, up, u4, n_nodes);
        edge_compute_kernel<<<nblk, 512, 0, stream>>>(
            u4, (const float4*)binary, index1, index2, bw,
            recs, cnts, offs, (float4*)bp, n_edges);
        bin_kernel<<<2 * NRANGE * NSLICE, 1024, 0, stream>>>(
            recs, cnts, offs, partials, nblk);
        merge_bin_kernel<<<(n_nodes + 255) / 256, 256, 0, stream>>>(
            partials, up, n_nodes);
    } else {
        // R4 fallback: packed u64 atomics (proven)
        unsigned long long* neg = (unsigned long long*)d_ws;
        unsigned long long* pos = neg + n_nodes;
        float4* u4 = (float4*)(pos + n_nodes);
        (void)hipMemsetAsync(neg, 0, (size_t)2 * n_nodes * 8, stream);
        unary_kernel<<<(n_nodes + 255) / 256, 256, 0, stream>>>(
            unary, uw, up, u4, n_nodes);
        edge_atomic_kernel<<<(n_edges + 255) / 256, 256, 0, stream>>>(
            up, (const float4*)binary, index1, index2, bw,
            neg, pos, (float4*)bp, n_edges);
        merge_atomic_kernel<<<(n_nodes + 255) / 256, 256, 0, stream>>>(
            neg, pos, up, n_nodes);
    }
}

// Round 16
// 153.178 us; speedup vs baseline: 3.9153x; 1.0706x over previous
//
#include <hip/hip_runtime.h>
#include <hip/hip_bf16.h>

// RelationalKENN, R14 (resubmit x3; R13/R14/R15-round benches were broker
// timeouts). 4x longer bucket segments (EPB 1024->4096).
//
// History: R5 bucket sort + LDS binning. R6-R8 block-private 8B-record
// slabs: edge 102->56us. R9 occupancy 49->61%: edge FLAT. R10 LDS-staged
// coalesced rec stores: total 159.6 (best). R11 nontemporal: NULL. R12
// fused cooperative: CATASTROPHIC (grid.sync spin across 8 XCD L2s).
// R13 NSLICE 16->8 (partials traffic halved): FLAT (164.0) -> bin+merge
// NOT BW-bound. Remaining hypothesis: bin is LATENCY-bound on short
// segments (~79 records per (chunk,side,range); ~2 load iters then a
// descriptor switch). R14: EPB 4096 (1024thr x 4 edges) -> segments ~315
// records, 4x fewer descriptor stalls; NSLICE back to 16. Edge reg
// pressure up -> launch_bounds(1024,4); R8/R9 proved edge
// occupancy-insensitive.
// Predict: edge ~48-58us flat; total ->148-152 if bin latency-bound;
// flat >=158 -> bin exonerated, non-edge mass is launch/harness floor.
//
// Layout: d_out = [ up : n_nodes*16 fp32 | bp : n_edges*4 fp32 ]
// ws = [ recs | partials | u4 | cnts | offs ]

#define NRANGE 13
#define RBITS  13
#define RSIZE  8192            // nodes per range (1 << RBITS)
#define NSLICE 16
#define EPB    4096            // edges per block (1024 threads x 4)
#define SEGCAP 4096            // records per side per block slab
#define FXP_SCALE 2048.0f      // 2^11; magnitudes <= 0.5 -> q <= 1024 (11b)
#define FXP_INV   (1.0f / 2048.0f)

__device__ __forceinline__ void sm2(float xi, float xj, float w,
                                    float& di, float& dj) {
    float na = -xi, b = xj;
    float m  = fmaxf(na, b);
    float e0 = __expf(na - m), e1 = __expf(b - m);
    float inv = w / (e0 + e1);
    di -= e0 * inv;
    dj += e1 * inv;
}

__device__ __forceinline__ void sm3(float xi, float xj, float xk, float w,
                                    float& di, float& dj, float& dk) {
    float na = -xi, b = xj, c = xk;
    float m  = fmaxf(fmaxf(na, b), c);
    float e0 = __expf(na - m), e1 = __expf(b - m), e2 = __expf(c - m);
    float inv = w / (e0 + e1 + e2);
    di -= e0 * inv;
    dj += e1 * inv;
    dk += e2 * inv;
}

__global__ void unary_kernel(const float* __restrict__ x_in,
                             const float* __restrict__ uw,
                             float* __restrict__ up,
                             float4* __restrict__ u4,      // compact cols 0..3
                             int n_nodes) {
    int n = blockIdx.x * blockDim.x + threadIdx.x;
    if (n >= n_nodes) return;

    const float4* xr = (const float4*)(x_in + (size_t)n * 16);
    float4 r0 = xr[0], r1 = xr[1], r2 = xr[2], r3 = xr[3];
    float x[16] = {r0.x, r0.y, r0.z, r0.w,
                   r1.x, r1.y, r1.z, r1.w,
                   r2.x, r2.y, r2.z, r2.w,
                   r3.x, r3.y, r3.z, r3.w};
    float d[16];
#pragma unroll
    for (int i = 0; i < 16; ++i) d[i] = 0.0f;

    sm2(x[0],  x[1],          uw[0], d[0],  d[1]);
    sm2(x[1],  x[2],          uw[1], d[1],  d[2]);
    sm3(x[2],  x[3],  x[4],   uw[2], d[2],  d[3],  d[4]);
    sm2(x[4],  x[5],          uw[3], d[4],  d[5]);
    sm3(x[6],  x[7],  x[8],   uw[4], d[6],  d[7],  d[8]);
    sm2(x[8],  x[9],          uw[5], d[8],  d[9]);
    sm3(x[10], x[11], x[12],  uw[6], d[10], d[11], d[12]);
    sm3(x[13], x[14], x[15],  uw[7], d[13], d[14], d[15]);

    float4* w_up = (float4*)(up + (size_t)n * 16);
    float4 v0 = make_float4(x[0] + d[0], x[1] + d[1], x[2] + d[2], x[3] + d[3]);
    w_up[0] = v0;
#pragma unroll
    for (int i = 1; i < 4; ++i)
        w_up[i] = make_float4(x[4*i]   + d[4*i],   x[4*i+1] + d[4*i+1],
                              x[4*i+2] + d[4*i+2], x[4*i+3] + d[4*i+3]);
    u4[n] = v0;
}

// ---------- fast path ----------

__global__ __launch_bounds__(1024, 4)
void edge_compute_kernel(const float4* __restrict__ u4,
                         const float4* __restrict__ binary,
                         const int* __restrict__ idx1,
                         const int* __restrict__ idx2,
                         const float* __restrict__ bw,
                         unsigned long long* __restrict__ recs, // [blk][2][SEGCAP]
                         unsigned* __restrict__ cnts,           // [blk][2][NRANGE]
                         unsigned* __restrict__ offs,           // [blk][2][NRANGE]
                         float4* __restrict__ bp,
                         int n_edges) {
    __shared__ unsigned cnt[2][NRANGE];
    __shared__ unsigned off[2][NRANGE];
    __shared__ __align__(16) unsigned long long stage[2][SEGCAP];  // 64 KB
    int tid = threadIdx.x;
    if (tid < 2 * NRANGE) ((unsigned*)cnt)[tid] = 0;
    __syncthreads();

    float w[4] = {bw[0], bw[1], bw[2], bw[3]};

    int e[4]; bool valid[4];
    int i1[4], i2[4], r1[4], r2[4];
    unsigned rank1[4], rank2[4];
    unsigned long long q1[4], q2[4];
    float4 b4[4], a4[4], c4[4], dbv4[4];

#pragma unroll
    for (int k = 0; k < 4; ++k) {
        e[k] = blockIdx.x * EPB + k * 1024 + tid;
        valid[k] = e[k] < n_edges;
        int ec = valid[k] ? e[k] : 0;
        i1[k] = idx1[ec];
        i2[k] = idx2[ec];
    }
#pragma unroll
    for (int k = 0; k < 4; ++k) {          // 8 gathers + 4 streams in flight
        a4[k] = u4[i1[k]];
        c4[k] = u4[i2[k]];
        b4[k] = binary[valid[k] ? e[k] : 0];
    }

#pragma unroll
    for (int k = 0; k < 4; ++k) {
        float a[4]  = {a4[k].x, a4[k].y, a4[k].z, a4[k].w};
        float bb[4] = {b4[k].x, b4[k].y, b4[k].z, b4[k].w};
        float c[4]  = {c4[k].x, c4[k].y, c4[k].z, c4[k].w};
        unsigned p1[4], p2[4];
        float dbv[4];
#pragma unroll
        for (int i = 0; i < 4; ++i) {
            // clause ([i, 32+i, 16+i], [-1,-1,+1]): sel = [-u1_i, -b_i, u2_i]
            float na = -a[i], nb = -bb[i], cc = c[i];
            float m  = fmaxf(fmaxf(na, nb), cc);
            float e0 = __expf(na - m), e1 = __expf(nb - m), e2 = __expf(cc - m);
            float inv = w[i] / (e0 + e1 + e2);
            p1[i]  = __float2uint_rn(e0 * inv * FXP_SCALE);  // |du1|
            p2[i]  = __float2uint_rn(e2 * inv * FXP_SCALE);  // du2
            dbv[i] = bb[i] - e1 * inv;
        }
        q1[k] = (unsigned long long)(unsigned)(i1[k] & (RSIZE - 1))
              | ((unsigned long long)p1[0] << 13) | ((unsigned long long)p1[1] << 25)
              | ((unsigned long long)p1[2] << 37) | ((unsigned long long)p1[3] << 49);
        q2[k] = (unsigned long long)(unsigned)(i2[k] & (RSIZE - 1))
              | ((unsigned long long)p2[0] << 13) | ((unsigned long long)p2[1] << 25)
              | ((unsigned long long)p2[2] << 37) | ((unsigned long long)p2[3] << 49);
        dbv4[k] = make_float4(dbv[0], dbv[1], dbv[2], dbv[3]);
        r1[k] = i1[k] >> RBITS;
        r2[k] = i2[k] >> RBITS;
        if (valid[k]) {
            rank1[k] = atomicAdd(&cnt[0][r1[k]], 1u);   // LDS atomic rank
            rank2[k] = atomicAdd(&cnt[1][r2[k]], 1u);
        }
    }
    __syncthreads();
    if (tid < 2) {                          // 13-entry exclusive scan per side
        unsigned acc = 0;
#pragma unroll
        for (int r = 0; r < NRANGE; ++r) { off[tid][r] = acc; acc += cnt[tid][r]; }
    }
    __syncthreads();
    if (tid < 2 * NRANGE) {                 // publish counts + offsets
        cnts[(size_t)blockIdx.x * 2 * NRANGE + tid] = ((unsigned*)cnt)[tid];
        offs[(size_t)blockIdx.x * 2 * NRANGE + tid] = ((unsigned*)off)[tid];
    }
#pragma unroll
    for (int k = 0; k < 4; ++k) {           // rank-scatter into LDS stage
        if (!valid[k]) continue;
        stage[0][off[0][r1[k]] + rank1[k]] = q1[k];
        stage[1][off[1][r2[k]] + rank2[k]] = q2[k];
        bp[e[k]] = dbv4[k];
    }
    __syncthreads();
    // stream slab out fully coalesced: 1024 thr x 4 x 16B
    ulonglong2* dst = (ulonglong2*)(recs + (size_t)blockIdx.x * 2 * SEGCAP);
    const ulonglong2* s0 = (const ulonglong2*)stage[0];
    const ulonglong2* s1 = (const ulonglong2*)stage[1];
    dst[tid]        = s0[tid];
    dst[1024 + tid] = s0[1024 + tid];
    dst[2048 + tid] = s1[tid];
    dst[3072 + tid] = s1[1024 + tid];
}

__global__ __launch_bounds__(1024)
void bin_kernel(const unsigned long long* __restrict__ recs,
                const unsigned* __restrict__ cnts,
                const unsigned* __restrict__ offs,
                unsigned long long* __restrict__ partials,
                int nblk) {
    __shared__ unsigned long long table[RSIZE];   // 64 KB static
    unsigned b    = blockIdx.x;                   // (side*NRANGE + r)*NSLICE + s
    unsigned s    = b % NSLICE;
    unsigned rr   = (b / NSLICE) % NRANGE;
    unsigned side = b / (NSLICE * NRANGE);

    for (int i = threadIdx.x; i < RSIZE; i += 1024) table[i] = 0ull;
    __syncthreads();

    unsigned bpg = ((unsigned)nblk + NSLICE - 1) / NSLICE;
    unsigned b0 = s * bpg;
    unsigned b1 = b0 + bpg;
    if (b1 > (unsigned)nblk) b1 = (unsigned)nblk;

    unsigned wid  = threadIdx.x >> 6;             // 16 waves walk independent
    unsigned lane = threadIdx.x & 63;             // sub-segments, stride 16
    unsigned eb = b0 + wid;
    unsigned c_cur = 0, o_cur = 0;
    if (eb < b1) {
        unsigned base = (eb * 2u + side) * NRANGE + rr;
        c_cur = cnts[base];
        o_cur = offs[base];
    }
    while (eb < b1) {
        unsigned eb_n = eb + 16;                  // prefetch next descriptor
        unsigned c_n = 0, o_n = 0;
        if (eb_n < b1) {
            unsigned base_n = (eb_n * 2u + side) * NRANGE + rr;
            c_n = cnts[base_n];
            o_n = offs[base_n];
        }
        const unsigned long long* seg =
            recs + ((size_t)eb * 2 + side) * SEGCAP + o_cur;
        unsigned i = lane;
        for (; i + 64 < c_cur; i += 128) {        // 2 loads in flight
            unsigned long long ra = seg[i];
            unsigned long long rb = seg[i + 64];
            unsigned long long va =  ((ra >> 13) & 0xFFFull)
                                  | (((ra >> 25) & 0xFFFull) << 16)
                                  | (((ra >> 37) & 0xFFFull) << 32)
                                  | (((ra >> 49) & 0xFFFull) << 48);
            unsigned long long vb =  ((rb >> 13) & 0xFFFull)
                                  | (((rb >> 25) & 0xFFFull) << 16)
                                  | (((rb >> 37) & 0xFFFull) << 32)
                                  | (((rb >> 49) & 0xFFFull) << 48);
            atomicAdd(&table[(unsigned)ra & (RSIZE - 1)], va);
            atomicAdd(&table[(unsigned)rb & (RSIZE - 1)], vb);
        }
        if (i < c_cur) {
            unsigned long long ra = seg[i];
            unsigned long long va =  ((ra >> 13) & 0xFFFull)
                                  | (((ra >> 25) & 0xFFFull) << 16)
                                  | (((ra >> 37) & 0xFFFull) << 32)
                                  | (((ra >> 49) & 0xFFFull) << 48);
            atomicAdd(&table[(unsigned)ra & (RSIZE - 1)], va);
        }
        eb = eb_n;
        c_cur = c_n;
        o_cur = o_n;
    }
    __syncthreads();

    unsigned long long* dst = partials + (size_t)b * RSIZE;
    for (int i2 = threadIdx.x; i2 < RSIZE; i2 += 1024) dst[i2] = table[i2];
}

__global__ void merge_bin_kernel(const unsigned long long* __restrict__ partials,
                                 float* __restrict__ up, int n_nodes) {
    int n = blockIdx.x * blockDim.x + threadIdx.x;
    if (n >= n_nodes) return;
    unsigned rr = (unsigned)n >> RBITS;
    unsigned i  = (unsigned)n & (RSIZE - 1);

    const unsigned long long* pn =
        partials + ((size_t)(0 * NRANGE + rr) * NSLICE) * RSIZE + i;
    const unsigned long long* pp =
        partials + ((size_t)(1 * NRANGE + rr) * NSLICE) * RSIZE + i;
    unsigned long long qn = 0, qp = 0;
#pragma unroll
    for (int sl = 0; sl < NSLICE; ++sl) {
        qn += pn[(size_t)sl * RSIZE];
        qp += pp[(size_t)sl * RSIZE];
    }

    float4* dst = (float4*)(up + (size_t)n * 16);
    float4 cur = dst[0];
    float d0 = ((float)(unsigned)( qp        & 0xFFFF) -
                (float)(unsigned)( qn        & 0xFFFF)) * FXP_INV;
    float d1 = ((float)(unsigned)((qp >> 16) & 0xFFFF) -
                (float)(unsigned)((qn >> 16) & 0xFFFF)) * FXP_INV;
    float d2 = ((float)(unsigned)((qp >> 32) & 0xFFFF) -
                (float)(unsigned)((qn >> 32) & 0xFFFF)) * FXP_INV;
    float d3 = ((float)(unsigned)((qp >> 48) & 0xFFFF) -
                (float)(unsigned)((qn >> 48) & 0xFFFF)) * FXP_INV;
    dst[0] = make_float4(cur.x + d0, cur.y + d1, cur.z + d2, cur.w + d3);
}

// ---------- fallback path (R4, proven): packed u64 global atomics ----------

__global__ void edge_atomic_kernel(const float* __restrict__ u,
                                   const float4* __restrict__ binary,
                                   const int* __restrict__ idx1,
                                   const int* __restrict__ idx2,
                                   const float* __restrict__ bw,
                                   unsigned long long* __restrict__ neg,
                                   unsigned long long* __restrict__ pos,
                                   float4* __restrict__ bp,
                                   int n_edges) {
    int e = blockIdx.x * blockDim.x + threadIdx.x;
    if (e >= n_edges) return;
    int n1 = idx1[e], n2 = idx2[e];
    float4 b4 = binary[e];
    float4 a4 = *(const float4*)(u + (size_t)n1 * 16);
    float4 c4 = *(const float4*)(u + (size_t)n2 * 16);
    float a[4]  = {a4.x, a4.y, a4.z, a4.w};
    float bb[4] = {b4.x, b4.y, b4.z, b4.w};
    float c[4]  = {c4.x, c4.y, c4.z, c4.w};
    unsigned long long q1 = 0, q2 = 0;
    float dbv[4];
#pragma unroll
    for (int i = 0; i < 4; ++i) {
        float na = -a[i], nb = -bb[i], cc = c[i];
        float m  = fmaxf(fmaxf(na, nb), cc);
        float e0 = __expf(na - m), e1 = __expf(nb - m), e2 = __expf(cc - m);
        float inv = bw[i] / (e0 + e1 + e2);
        q1 |= (unsigned long long)__float2uint_rn(e0 * inv * FXP_SCALE) << (16 * i);
        q2 |= (unsigned long long)__float2uint_rn(e2 * inv * FXP_SCALE) << (16 * i);
        dbv[i] = bb[i] - e1 * inv;
    }
    atomicAdd(&neg[n1], q1);
    atomicAdd(&pos[n2], q2);
    bp[e] = make_float4(dbv[0], dbv[1], dbv[2], dbv[3]);
}

__global__ void merge_atomic_kernel(const unsigned long long* __restrict__ neg,
                                    const unsigned long long* __restrict__ pos,
                                    float* __restrict__ up, int n_nodes) {
    int n = blockIdx.x * blockDim.x + threadIdx.x;
    if (n >= n_nodes) return;
    unsigned long long qn = neg[n], qp = pos[n];
    float4* dst = (float4*)(up + (size_t)n * 16);
    float4 cur = dst[0];
    float d0 = ((float)(unsigned)( qp        & 0xFFFF) -
                (float)(unsigned)( qn        & 0xFFFF)) * FXP_INV;
    float d1 = ((float)(unsigned)((qp >> 16) & 0xFFFF) -
                (float)(unsigned)((qn >> 16) & 0xFFFF)) * FXP_INV;
    float d2 = ((float)(unsigned)((qp >> 32) & 0xFFFF) -
                (float)(unsigned)((qn >> 32) & 0xFFFF)) * FXP_INV;
    float d3 = ((float)(unsigned)((qp >> 48) & 0xFFFF) -
                (float)(unsigned)((qn >> 48) & 0xFFFF)) * FXP_INV;
    dst[0] = make_float4(cur.x + d0, cur.y + d1, cur.z + d2, cur.w + d3);
}

extern "C" void kernel_launch(void* const* d_in, const int* in_sizes, int n_in,
                              void* d_out, int out_size, void* d_ws, size_t ws_size,
                              hipStream_t stream) {
    const float* unary   = (const float*)d_in[0];
    const float* binary  = (const float*)d_in[1];
    const int*   index1  = (const int*)d_in[2];
    const int*   index2  = (const int*)d_in[3];
    const float* uw      = (const float*)d_in[4];
    const float* bw      = (const float*)d_in[5];

    int n_nodes = in_sizes[0] / 16;
    int n_edges = in_sizes[2];

    float* out = (float*)d_out;
    float* up  = out;                                // n_nodes*16
    float* bp  = out + (size_t)n_nodes * 16;         // n_edges*4

    int nblk = (n_edges + EPB - 1) / EPB;            // 489 @ 2M edges

    // ws layout (fast path): recs | partials | u4 | cnts | offs
    size_t rec_bytes  = (size_t)nblk * 2 * SEGCAP * 8;                   // 32.05 MB
    size_t part_bytes = (size_t)2 * NRANGE * NSLICE * RSIZE * 8;         // 27.26 MB
    size_t u4_bytes   = (size_t)n_nodes * 16;                            // 1.6 MB
    size_t cnt_bytes  = (size_t)nblk * 2 * NRANGE * 4;                   // ~51 KB
    size_t need = rec_bytes + part_bytes + u4_bytes + 2 * cnt_bytes + 256;

    if (ws_size >= need) {
        char* w = (char*)d_ws;
        unsigned long long* recs     = (unsigned long long*)w;
        unsigned long long* partials = (unsigned long long*)(w + rec_bytes);
        float4*   u4   = (float4*)(w + rec_bytes + part_bytes);
        unsigned* cnts = (unsigned*)(w + rec_bytes + part_bytes + u4_bytes);
        unsigned* offs = cnts + (size_t)nblk * 2 * NRANGE;

        unary_kernel<<<(n_nodes + 255) / 256, 256, 0, stream>>>(
            unary, uw, up, u4, n_nodes);
        edge_compute_kernel<<<nblk, 1024, 0, stream>>>(
            u4, (const float4*)binary, index1, index2, bw,
            recs, cnts, offs, (float4*)bp, n_edges);
        bin_kernel<<<2 * NRANGE * NSLICE, 1024, 0, stream>>>(
            recs, cnts, offs, partials, nblk);
        merge_bin_kernel<<<(n_nodes + 255) / 256, 256, 0, stream>>>(
            partials, up, n_nodes);
    } else {
        // R4 fallback: packed u64 atomics (proven)
        unsigned long long* neg = (unsigned long long*)d_ws;
        unsigned long long* pos = neg + n_nodes;
        float4* u4 = (float4*)(pos + n_nodes);
        (void)hipMemsetAsync(neg, 0, (size_t)2 * n_nodes * 8, stream);
        unary_kernel<<<(n_nodes + 255) / 256, 256, 0, stream>>>(
            unary, uw, up, u4, n_nodes);
        edge_atomic_kernel<<<(n_edges + 255) / 256, 256, 0, stream>>>(
            up, (const float4*)binary, index1, index2, bw,
            neg, pos, (float4*)bp, n_edges);
        merge_atomic_kernel<<<(n_nodes + 255) / 256, 256, 0, stream>>>(
            neg, pos, up, n_nodes);
    }
}